// Round 9
// baseline (102.978 us; speedup 1.0000x reference)
//
#include <hip/hip_runtime.h>
#include <math.h>

#define N 4096
#define FEPS 1e-7f
#define HEPS 5e-8f      // FEPS/2, split across the two records of a pair
#define BLK 256
#define JT 64           // grid = 16*64 = 1024 blocks = 4 blocks/CU = 4 waves/SIMD
#define CH 64           // j's per block
#define NPAIR (CH / 2)  // 32 packed j-pairs per block
#define KATAN 0.6366197723675814f   // 2/pi (folds 4/pi^2 into atan)
#define SQL2E 1.2011224087864498f   // sqrt(log2 e), folds exp->exp2 into conf

typedef float v2f __attribute__((ext_vector_type(2)));

// ============================ r9: MEASUREMENT ROUND =========================
// After 8 rounds, the main/epilogue split has NEVER been observed (top-5
// counter rows are always the 41us poison fills; every theory was built on
// an assumed split, and pipe/latency/occupancy/inst-count theories all came
// back neutral-or-worse while models say main should cost <=8us of the ~40us
// controllable budget). This round dispatches the BIT-IDENTICAL main kernel
// TWICE (second into a disjoint part2 region); epilogue sums both partial
// sets. Both mains are deterministic+identical -> every epilogue operand is
// exactly 2x r8's -> (2A)/(2S) is bit-identical to A/S -> output unchanged.
// The dur_us delta vs r8 (81.3) IS the main kernel's true duration:
//   ~112-118 -> main ~33us (attack main at disasm level next)
//   ~87-92   -> main ~7-10us (attack epilogue latency + dispatch overhead)
// ===========================================================================
//
// d_ws: part[jt][c][i] : JT*6*N floats = 6.29 MB, then part2 same = 12.6 MB.
// Kept (absmax=0 through r8): packed-v2f one-rcp common-denominator CIoU:
//   P=(v+1+eps)*uni-inter (=den*uni, clamp>=1e-12; cancels in the ratio on
//   the diagonal), ciou=[P*(inter*c2-rho2*uni)-v^2*uni^2*c2]/(uni*c2*P);
// eps split across records, 4/pi^2 folded into atan, log2e folded into conf.
// NO 2nd __launch_bounds__ arg (measured: forcing waves/EU spills/regresses).

__device__ __forceinline__ v2f min2(v2f a, v2f b) {
    v2f r; r.x = fminf(a.x, b.x); r.y = fminf(a.y, b.y); return r;
}
__device__ __forceinline__ v2f max2(v2f a, v2f b) {
    v2f r; r.x = fmaxf(a.x, b.x); r.y = fmaxf(a.y, b.y); return r;
}
__device__ __forceinline__ v2f rcp2(v2f a) {
    v2f r; r.x = __builtin_amdgcn_rcpf(a.x); r.y = __builtin_amdgcn_rcpf(a.y); return r;
}
__device__ __forceinline__ v2f exp22(v2f a) {
    v2f r; r.x = __builtin_amdgcn_exp2f(a.x); r.y = __builtin_amdgcn_exp2f(a.y); return r;
}

// Packed-SoA pair records in LDS: field k of pair p, slot s (s=j&1) at
// jrec[p*24 + k*2 + s]. Fields: 0:x1 1:y1 2:x2 3:y2 4:hx 5:hy 6:w 7:h
// 8:area+eps/2 9:atan-folded 10:cf*sqrt(log2e) 11:cf
__global__ __launch_bounds__(BLK) void ciou_attn_kernel(
        const float* __restrict__ x,
        float* __restrict__ part) {
    __shared__ float jrec[NPAIR * 24];   // 3 KB
    const int tid = threadIdx.x;
    const int gb = blockIdx.x / JT;
    const int jt = blockIdx.x % JT;
    const int i = gb * BLK + tid;

    // Stage j-chunk in-kernel (first CH threads; one atanf each).
    if (tid < CH) {
        int j = jt * CH + tid;
        float cf = x[j * 5 + 0], jx1 = x[j * 5 + 1], jy1 = x[j * 5 + 2];
        float jx2 = x[j * 5 + 3], jy2 = x[j * 5 + 4];
        float w = jx2 - jx1, h = jy2 - jy1;
        float* dp = &jrec[(tid >> 1) * 24 + (tid & 1)];
        dp[0]  = jx1;               dp[2]  = jy1;
        dp[4]  = jx2;               dp[6]  = jy2;
        dp[8]  = (jx1 + jx2) * 0.5f; dp[10] = (jy1 + jy2) * 0.5f;
        dp[12] = w;                 dp[14] = h;
        dp[16] = fmaf(w, h, HEPS);
        dp[18] = KATAN * atanf(w / (h + FEPS));
        dp[20] = cf * SQL2E;        dp[22] = cf;
    }

    // Per-lane row record.
    const float rx1 = x[i * 5 + 1], ry1 = x[i * 5 + 2];
    const float rx2 = x[i * 5 + 3], ry2 = x[i * 5 + 4];
    const float rw = rx2 - rx1, rh = ry2 - ry1;
    const float rhx = (rx1 + rx2) * 0.5f, rhy = (ry1 + ry2) * 0.5f;
    const float rareps = fmaf(rw, rh, HEPS);
    const float rat = KATAN * atanf(rw / (rh + FEPS));
    const float rcf2 = x[i * 5 + 0] * SQL2E;

    __syncthreads();

    v2f sum = 0.f, a0 = 0.f, a1 = 0.f, a2 = 0.f, a3 = 0.f, a4 = 0.f;
    const float ONEP = 1.f + FEPS;

#pragma unroll 4
    for (int p = 0; p < NPAIR; p++) {
        const float* f = &jrec[p * 24];   // uniform addr -> broadcast reads
        const v2f X1 = *(const v2f*)(f + 0),  Y1 = *(const v2f*)(f + 2);
        const v2f X2 = *(const v2f*)(f + 4),  Y2 = *(const v2f*)(f + 6);
        const v2f HX = *(const v2f*)(f + 8),  HY = *(const v2f*)(f + 10);
        const v2f W  = *(const v2f*)(f + 12), H  = *(const v2f*)(f + 14);
        const v2f AR = *(const v2f*)(f + 16), AT = *(const v2f*)(f + 18);
        const v2f CF2 = *(const v2f*)(f + 20), CF = *(const v2f*)(f + 22);

        v2f iwr = min2(rx2, X2) - max2(rx1, X1);
        v2f ihr = min2(ry2, Y2) - max2(ry1, Y1);
        v2f inter = max2(iwr, 0.f) * max2(ihr, 0.f);
        v2f uni = (rareps + AR) - inter;
        v2f cw = (rw + W) - iwr;             // enclosing box identity
        v2f chh = (rh + H) - ihr;
        v2f c2 = cw * cw + chh * chh + FEPS;
        v2f dx = HX - rhx;
        v2f dy = HY - rhy;
        v2f rho2 = dx * dx + dy * dy;        // /4 pre-folded
        v2f da = AT - rat;                   // 4/pi^2 pre-folded
        v2f v = da * da;
        v2f P = (v + ONEP) * uni - inter;    // den*uni
        P = max2(P, 1e-12f);                 // fp-cancellation guard
        v2f rr = rcp2(uni * c2 * P);         // one rcp per pair
        v2f t1 = inter * c2 - rho2 * uni;
        v2f vu = v * uni;
        v2f num = t1 * P - (vu * vu) * c2;
        v2f e = exp22((num * rr) * (rcf2 * CF2));
        sum += e;
        a0 += e * CF;
        a1 += e * X1;
        a2 += e * Y1;
        a3 += e * X2;
        a4 += e * Y2;
    }

    // Coalesced partial stores: [jt][c][i], lanes contiguous in i.
    float* p = part + (size_t)jt * 6 * N;
    p[0 * N + i] = sum.x + sum.y;
    p[1 * N + i] = a0.x + a0.y;
    p[2 * N + i] = a1.x + a1.y;
    p[3 * N + i] = a2.x + a2.y;
    p[4 * N + i] = a3.x + a3.y;
    p[5 * N + i] = a4.x + a4.y;
}

// Sums BOTH partial sets (pa exactly == pb -> operands exactly doubled ->
// a/se bit-identical to the single-set result).
__global__ void epilogue_kernel(const float* __restrict__ x,
                                const float* __restrict__ gamma,
                                const float* __restrict__ pa,
                                const float* __restrict__ pb,
                                float* __restrict__ out) {
    int idx = blockIdx.x * blockDim.x + threadIdx.x;
    if (idx >= N * 5) return;
    int c = idx / N, i = idx - c * N;
    float se = 0.f, a = 0.f;
#pragma unroll 8
    for (int jt = 0; jt < JT; jt++) {
        const float* p1 = pa + (size_t)jt * 6 * N;
        const float* p2 = pb + (size_t)jt * 6 * N;
        se += p1[0 * N + i] + p2[0 * N + i];
        a  += p1[(1 + c) * N + i] + p2[(1 + c) * N + i];
    }
    float xp = x[i * 5 + c] * gamma[0] + a / se;
    out[i * 5 + c] = 1.f / (1.f + expf(-xp));
}

extern "C" void kernel_launch(void* const* d_in, const int* in_sizes, int n_in,
                              void* d_out, int out_size, void* d_ws, size_t ws_size,
                              hipStream_t stream) {
    const float* x = (const float*)d_in[0];
    const float* gamma = (const float*)d_in[1];
    float* out = (float*)d_out;
    float* part = (float*)d_ws;                    // 6.29 MB
    float* part2 = part + (size_t)JT * 6 * N;      // 6.29 MB

    ciou_attn_kernel<<<(N / BLK) * JT, BLK, 0, stream>>>(x, part);
    ciou_attn_kernel<<<(N / BLK) * JT, BLK, 0, stream>>>(x, part2);  // timing probe
    epilogue_kernel<<<(N * 5 + 255) / 256, 256, 0, stream>>>(x, gamma, part, part2, out);
}

// Round 10
// 77.752 us; speedup vs baseline: 1.3244x; 1.3244x over previous
//
#include <hip/hip_runtime.h>
#include <math.h>

#define N 4096
#define FEPS 1e-7f
#define HEPS 5e-8f      // FEPS/2, split across the two records of a pair
#define BLK 256
#define JT 64           // grid = 16*64 = 1024 blocks = 4 blocks/CU = 4 waves/SIMD
#define CH 64           // j's per block
#define NPAIR (CH / 2)  // 32 packed j-pairs per block
#define KATAN 0.6366197723675814f   // 2/pi (folds 4/pi^2 into atan)
#define SQL2E 1.2011224087864498f   // sqrt(log2 e), folds exp->exp2 into conf
#define ISQL2E 0.8325546111576977f  // 1/SQL2E, unfolds cf2 in a0 (r5: absmax 0)

typedef float v2f __attribute__((ext_vector_type(2)));

// d_ws: part[jt][c][i] : JT*6*N floats = 6.29 MB.
//
// r10 (r9 MEASURED main = 103.0-81.3 = ~20us incl. gap; fill 41.3 fixed;
// epilogue+gaps ~20us): main matches the LDS-PIPE model, not the VALU model:
// the 12 adjacent v2f broadcast reads merge to 6 ds_read_b128/iter; LDS pipe
// is per-CU shared by 16 waves -> 6*12cy*32it*16w = 37k cyc = 15.4us/CU
// (VALU only 6.6us/SIMD). Explains r0..r8: relocating the broadcast or
// halving VALU never moved total; adding VALU/latency regressed.
// Changes:
//  1. LDS record 12 -> 6 fields/j (x1,y1,x2,y2,atan,cf2): 3 b128/iter.
//     W,H,HX,HY,AR derived in-loop on v2f (+7 inst on the idle VALU pipe).
//     a0 accumulates e*CF2, unfolded by ISQL2E at store (r5 measured safe).
//     LDS/CU -> 7.7us; predicted main ~10-12us.
//  2. epilogue: 4 threads/output (16 jt-slots each) + LDS cross-reduce ->
//     1280 waves (was 320), predicted ~3us. Sum-order changes (64-term
//     reduction now 16x4 tree): expected absmax <=1e-6, accepted.
//
// Kept (absmax=0 through r9): packed-v2f one-rcp common-denominator CIoU:
//   P=(v+1+eps)*uni-inter (=den*uni, clamp>=1e-12; cancels in the ratio on
//   the diagonal), ciou=[P*(inter*c2-rho2*uni)-v^2*uni^2*c2]/(uni*c2*P);
// eps split across records, 4/pi^2 folded into atan, log2e folded into conf.
// NO 2nd __launch_bounds__ arg (measured: forcing waves/EU spills/regresses).

__device__ __forceinline__ v2f min2(v2f a, v2f b) {
    v2f r; r.x = fminf(a.x, b.x); r.y = fminf(a.y, b.y); return r;
}
__device__ __forceinline__ v2f max2(v2f a, v2f b) {
    v2f r; r.x = fmaxf(a.x, b.x); r.y = fmaxf(a.y, b.y); return r;
}
__device__ __forceinline__ v2f rcp2(v2f a) {
    v2f r; r.x = __builtin_amdgcn_rcpf(a.x); r.y = __builtin_amdgcn_rcpf(a.y); return r;
}
__device__ __forceinline__ v2f exp22(v2f a) {
    v2f r; r.x = __builtin_amdgcn_exp2f(a.x); r.y = __builtin_amdgcn_exp2f(a.y); return r;
}

// Packed-SoA pair records in LDS: pair p stride 12 floats (48 B, 16-aligned):
// [x1a,x1b, y1a,y1b, x2a,x2b, y2a,y2b, ata,atb, cf2a,cf2b]
__global__ __launch_bounds__(BLK) void ciou_attn_kernel(
        const float* __restrict__ x,
        float* __restrict__ part) {
    __shared__ float jrec[NPAIR * 12];   // 1.5 KB
    const int tid = threadIdx.x;
    const int gb = blockIdx.x / JT;
    const int jt = blockIdx.x % JT;
    const int i = gb * BLK + tid;

    // Stage j-chunk in-kernel (first CH threads; one atanf each).
    if (tid < CH) {
        int j = jt * CH + tid;
        float cf = x[j * 5 + 0], jx1 = x[j * 5 + 1], jy1 = x[j * 5 + 2];
        float jx2 = x[j * 5 + 3], jy2 = x[j * 5 + 4];
        float* dp = &jrec[(tid >> 1) * 12 + (tid & 1)];
        dp[0]  = jx1;  dp[2] = jy1;  dp[4] = jx2;  dp[6] = jy2;
        dp[8]  = KATAN * atanf((jx2 - jx1) / ((jy2 - jy1) + FEPS));
        dp[10] = cf * SQL2E;
    }

    // Per-lane row record.
    const float rx1 = x[i * 5 + 1], ry1 = x[i * 5 + 2];
    const float rx2 = x[i * 5 + 3], ry2 = x[i * 5 + 4];
    const float rw = rx2 - rx1, rh = ry2 - ry1;
    const float rhx = (rx1 + rx2) * 0.5f, rhy = (ry1 + ry2) * 0.5f;
    const float rareps = fmaf(rw, rh, HEPS);
    const float rat = KATAN * atanf(rw / (rh + FEPS));
    const float rcf2 = x[i * 5 + 0] * SQL2E;

    __syncthreads();

    v2f sum = 0.f, a0 = 0.f, a1 = 0.f, a2 = 0.f, a3 = 0.f, a4 = 0.f;
    const float ONEP = 1.f + FEPS;

#pragma unroll 4
    for (int p = 0; p < NPAIR; p++) {
        const float* f = &jrec[p * 12];   // uniform addr -> 3x b128 broadcast
        const v2f X1 = *(const v2f*)(f + 0),  Y1 = *(const v2f*)(f + 2);
        const v2f X2 = *(const v2f*)(f + 4),  Y2 = *(const v2f*)(f + 6);
        const v2f AT = *(const v2f*)(f + 8),  CF2 = *(const v2f*)(f + 10);
        // Derived j-fields in VALU (the non-bottleneck pipe).
        const v2f W = X2 - X1, H = Y2 - Y1;
        const v2f HX = (X1 + X2) * 0.5f, HY = (Y1 + Y2) * 0.5f;
        const v2f AR = W * H + HEPS;

        v2f iwr = min2(rx2, X2) - max2(rx1, X1);
        v2f ihr = min2(ry2, Y2) - max2(ry1, Y1);
        v2f inter = max2(iwr, 0.f) * max2(ihr, 0.f);
        v2f uni = (rareps + AR) - inter;
        v2f cw = (rw + W) - iwr;             // enclosing box identity
        v2f chh = (rh + H) - ihr;
        v2f c2 = cw * cw + chh * chh + FEPS;
        v2f dx = HX - rhx;
        v2f dy = HY - rhy;
        v2f rho2 = dx * dx + dy * dy;        // /4 pre-folded
        v2f da = AT - rat;                   // 4/pi^2 pre-folded
        v2f v = da * da;
        v2f P = (v + ONEP) * uni - inter;    // den*uni
        P = max2(P, 1e-12f);                 // fp-cancellation guard
        v2f rr = rcp2(uni * c2 * P);         // one rcp per pair
        v2f t1 = inter * c2 - rho2 * uni;
        v2f vu = v * uni;
        v2f num = t1 * P - (vu * vu) * c2;
        v2f e = exp22((num * rr) * (rcf2 * CF2));
        sum += e;
        a0 += e * CF2;                        // cf2-folded; unfold at store
        a1 += e * X1;
        a2 += e * Y1;
        a3 += e * X2;
        a4 += e * Y2;
    }

    // Coalesced partial stores: [jt][c][i], lanes contiguous in i.
    float* p = part + (size_t)jt * 6 * N;
    p[0 * N + i] = sum.x + sum.y;
    p[1 * N + i] = (a0.x + a0.y) * ISQL2E;
    p[2 * N + i] = a1.x + a1.y;
    p[3 * N + i] = a2.x + a2.y;
    p[4 * N + i] = a3.x + a3.y;
    p[5 * N + i] = a4.x + a4.y;
}

// 4 threads per output element: thread (o=t&63, q=t>>6) sums jt-slots
// [q*16, q*16+16); LDS reduce across q; t<64 finishes. 320 blocks = 1280
// waves (4x the old 320) -> load latency hidden. All part loads coalesced
// (block's 64 outputs share c since 64 | N, i contiguous).
__global__ void epilogue_kernel(const float* __restrict__ x,
                                const float* __restrict__ gamma,
                                const float* __restrict__ part,
                                float* __restrict__ out) {
    __shared__ float red[2][BLK];
    const int t = threadIdx.x;
    const int o = t & 63, q = t >> 6;
    const int idx = blockIdx.x * 64 + o;
    const int c = idx / N, i = idx - c * N;
    float se = 0.f, a = 0.f;
    const float* ps = part + (size_t)(q * 16) * 6 * N;
#pragma unroll
    for (int k = 0; k < 16; k++) {
        const float* p = ps + (size_t)k * 6 * N;
        se += p[0 * N + i];
        a  += p[(1 + c) * N + i];
    }
    red[0][t] = se; red[1][t] = a;
    __syncthreads();
    if (t < 64) {
        float se4 = (red[0][t] + red[0][t + 64]) + (red[0][t + 128] + red[0][t + 192]);
        float a4  = (red[1][t] + red[1][t + 64]) + (red[1][t + 128] + red[1][t + 192]);
        float xp = x[i * 5 + c] * gamma[0] + a4 / se4;
        out[i * 5 + c] = 1.f / (1.f + expf(-xp));
    }
}

extern "C" void kernel_launch(void* const* d_in, const int* in_sizes, int n_in,
                              void* d_out, int out_size, void* d_ws, size_t ws_size,
                              hipStream_t stream) {
    const float* x = (const float*)d_in[0];
    const float* gamma = (const float*)d_in[1];
    float* out = (float*)d_out;
    float* part = (float*)d_ws;  // JT*6*N floats = 6.29 MB

    ciou_attn_kernel<<<(N / BLK) * JT, BLK, 0, stream>>>(x, part);
    epilogue_kernel<<<(N * 5) / 64, BLK, 0, stream>>>(x, gamma, part, out);
}